// Round 21
// baseline (1052.486 us; speedup 1.0000x reference)
//
#include <hip/hip_runtime.h>
#include <cstdint>
#include <cstddef>

#define KNB 20
#define NPTS 8192
#define BATCH 2
#define TOTAL (BATCH * NPTS)

// ---------------------------------------------------------------------------
// K0: transpose pts to SoA for coalesced, L1-hot KNN candidate reads.
// ---------------------------------------------------------------------------
__global__ __launch_bounds__(256) void k_pose(const float* __restrict__ pts,
                                              float* __restrict__ ptsT) {
  int gid = blockIdx.x * 256 + threadIdx.x;
  if (gid >= TOTAL * 3) return;
  int pt = gid / 3, d = gid % 3;
  int b = pt >> 13, p = pt & (NPTS - 1);
  ptsT[((size_t)b * 3 + d) * NPTS + p] = pts[gid];
}

// ---------------------------------------------------------------------------
// K1: pointwise conv 3->64 + relu
// ---------------------------------------------------------------------------
__global__ __launch_bounds__(256) void k_conv(const float* __restrict__ pts,
                                              const float* __restrict__ w,
                                              const float* __restrict__ b,
                                              float* __restrict__ x0) {
  int gid = blockIdx.x * 256 + threadIdx.x;
  if (gid >= TOTAL * 64) return;
  int p = gid >> 6, c = gid & 63;
  float px = pts[p * 3 + 0], py = pts[p * 3 + 1], pz = pts[p * 3 + 2];
  float acc = b[c] + px * w[c] + py * w[64 + c] + pz * w[128 + c];
  x0[gid] = fmaxf(acc, 0.f);
}

// ---------------------------------------------------------------------------
// K2: KNN v7 — R20 (289 µs, VALU 74%) + TWO-SEGMENT insert. VALU time is
// insert-chain dominated (~14K cyc/wave model); passes with d2 >= dist[9]
// (~half) now run only the 10-deep high-segment chain. Exactness: the
// restricted chain's j=10 step compares d2 < dist[9] == false (branch
// condition), so d2 lands at position 10; strict-< tie order unchanged;
// resulting sorted-20 list is identical to the full chain's.
// d2 via __fmul_rn/__fadd_rn: bit-identical to numpy's ((dx²+dy²)+dz²).
// ---------------------------------------------------------------------------
__global__ __launch_bounds__(256) void k_knn(const float* __restrict__ ptsT,
                                             const float* __restrict__ pts,
                                             int* __restrict__ idxbuf) {
  int tid = threadIdx.x;
  int wv = tid >> 6, lane = tid & 63;
  int q = blockIdx.x * 4 + wv;
  int bq = q >> 13;
  const float* px = ptsT + (size_t)bq * 3 * NPTS;
  const float* py = px + NPTS;
  const float* pz = py + NPTS;
  float qx = pts[q * 3 + 0], qy = pts[q * 3 + 1], qz = pts[q * 3 + 2];

  float dist[KNB];
  int id[KNB];
#pragma unroll
  for (int j = 0; j < KNB; j++) { dist[j] = 3.402823466e38f; id[j] = 0; }
  float tau = 3.402823466e38f;

#define INSERT(D2, CID)                                                      \
  if ((D2) <= tau && (D2) < dist[KNB - 1]) {                                 \
    int cid_ = (CID);                                                        \
    if ((D2) < dist[9]) {                                                    \
      _Pragma("unroll")                                                      \
      for (int j = KNB - 1; j >= 0; j--) {                                   \
        bool cj = (D2) < dist[j];                                            \
        bool cjm1 = (j > 0) && ((D2) < dist[j - 1]);                         \
        if (cj) {                                                            \
          dist[j] = cjm1 ? dist[j - 1] : (D2);                               \
          id[j]   = cjm1 ? id[j - 1]   : cid_;                               \
        }                                                                    \
      }                                                                      \
    } else {                                                                 \
      _Pragma("unroll")                                                      \
      for (int j = KNB - 1; j >= 10; j--) {                                  \
        bool cj = (D2) < dist[j];                                            \
        bool cjm1 = (D2) < dist[j - 1];                                      \
        if (cj) {                                                            \
          dist[j] = cjm1 ? dist[j - 1] : (D2);                               \
          id[j]   = cjm1 ? id[j - 1]   : cid_;                               \
        }                                                                    \
      }                                                                      \
    }                                                                        \
  }

  for (int chunk = 0; chunk < 8; chunk++) {
    if (chunk) {
      // tau = 20th smallest of the 64 lane-head d2 values (f32 bitonic).
      float h = dist[0];
#pragma unroll
      for (int k = 2; k <= 64; k <<= 1) {
#pragma unroll
        for (int j = k >> 1; j > 0; j >>= 1) {
          float o = __shfl_xor(h, j);
          bool up = ((lane & k) == 0);
          bool lower = ((lane & j) == 0);
          bool takeMin = (up == lower);
          bool lt = h < o;
          h = (takeMin == lt) ? h : o;
        }
      }
      tau = __shfl(h, 19);
    }

    int base = chunk * 1024;
#pragma unroll
    for (int g = 0; g < 4; g++) {
      int cb = base + g * 256 + lane * 4;
      float4 x4 = *(const float4*)&px[cb];
      float4 y4 = *(const float4*)&py[cb];
      float4 z4 = *(const float4*)&pz[cb];
      float dx0 = qx - x4.x, dy0 = qy - y4.x, dz0 = qz - z4.x;
      float dx1 = qx - x4.y, dy1 = qy - y4.y, dz1 = qz - z4.y;
      float dx2 = qx - x4.z, dy2 = qy - y4.z, dz2 = qz - z4.z;
      float dx3 = qx - x4.w, dy3 = qy - y4.w, dz3 = qz - z4.w;
      float d0 = __fadd_rn(__fadd_rn(__fmul_rn(dx0, dx0), __fmul_rn(dy0, dy0)),
                           __fmul_rn(dz0, dz0));
      float d1 = __fadd_rn(__fadd_rn(__fmul_rn(dx1, dx1), __fmul_rn(dy1, dy1)),
                           __fmul_rn(dz1, dz1));
      float d2v = __fadd_rn(__fadd_rn(__fmul_rn(dx2, dx2), __fmul_rn(dy2, dy2)),
                            __fmul_rn(dz2, dz2));
      float d3 = __fadd_rn(__fadd_rn(__fmul_rn(dx3, dx3), __fmul_rn(dy3, dy3)),
                           __fmul_rn(dz3, dz3));
      INSERT(d0, cb + 0)
      INSERT(d1, cb + 1)
      INSERT(d2v, cb + 2)
      INSERT(d3, cb + 3)
    }
  }
#undef INSERT

  // 20-step cross-lane merge: min over packed (d2bits, cid) — exact
  // lax.top_k order (d2 asc, index asc).
  int bqoff = bq * NPTS;
  for (int step = 0; step < KNB; step++) {
    unsigned long long p =
        ((unsigned long long)__float_as_uint(dist[0]) << 32) | (unsigned)id[0];
    unsigned long long m = p;
#pragma unroll
    for (int off = 32; off >= 1; off >>= 1) {
      unsigned long long o = __shfl_xor(m, off);
      m = (o < m) ? o : m;
    }
    if (lane == 0) idxbuf[q * KNB + step] = bqoff + (int)(m & 0xffffffffULL);
    if (p == m) {
#pragma unroll
      for (int j = 0; j < KNB - 1; j++) { dist[j] = dist[j + 1]; id[j] = id[j + 1]; }
      dist[KNB - 1] = 3.402823466e38f;
    }
  }
}

// ---------------------------------------------------------------------------
// K3c: per-layer weight folding: W2 = pw2@aw1_bot, c0 = pb2@aw1_bot.
// ---------------------------------------------------------------------------
__global__ __launch_bounds__(256) void k_w2(const float* __restrict__ pw2,
                                            const float* __restrict__ pb2,
                                            const float* __restrict__ aw1,
                                            float* __restrict__ W2,
                                            float* __restrict__ c0) {
  int h = blockIdx.x, c = threadIdx.x;
  float a = 0.f;
  if (h < 64) {
#pragma unroll 8
    for (int j = 0; j < 64; j++)
      a += pw2[h * 64 + j] * aw1[(size_t)(64 + j) * 256 + c];
    W2[h * 256 + c] = a;
  } else {
#pragma unroll 8
    for (int j = 0; j < 64; j++)
      a += pb2[j] * aw1[(size_t)(64 + j) * 256 + c];
    c0[c] = a;
  }
}

// ---------------------------------------------------------------------------
// K3: FUSED qkv + kh + qh (R19, proven).
// ---------------------------------------------------------------------------
__global__ __launch_bounds__(256) void k_pre(const float* __restrict__ x,
                                             const float* __restrict__ w,
                                             const float* __restrict__ aw1,
                                             const float* __restrict__ c0,
                                             float* __restrict__ v,
                                             float* __restrict__ kh,
                                             float* __restrict__ qh) {
  int tid = threadIdx.x;
  int wv = tid >> 6, lane = tid & 63;
  int p = blockIdx.x * 4 + wv;
  const float* xr = x + (size_t)p * 64;

  float qa = 0.f, ka = 0.f, va = 0.f;
#pragma unroll 8
  for (int h = 0; h < 64; h++) {
    float xv = xr[h];
    qa += xv * w[h * 192 + lane];
    ka += xv * w[h * 192 + 64 + lane];
    va += xv * w[h * 192 + 128 + lane];
  }
  v[(size_t)p * 64 + lane] = va;

#define RL(x_, l_) __uint_as_float(__builtin_amdgcn_readlane(__float_as_uint(x_), (l_)))
  int c4 = lane * 4;
  float4 a = make_float4(0.f, 0.f, 0.f, 0.f);
#pragma unroll 8
  for (int h = 0; h < 64; h++) {
    float kb = RL(ka, h);
    float4 wv4 = *(const float4*)&aw1[(size_t)h * 256 + c4];
    a.x += kb * wv4.x; a.y += kb * wv4.y; a.z += kb * wv4.z; a.w += kb * wv4.w;
  }
  *(float4*)&kh[(size_t)p * 256 + c4] = a;

  float4 b = make_float4(0.f, 0.f, 0.f, 0.f);
#pragma unroll 8
  for (int h = 0; h < 64; h++) {
    float qb = RL(qa, h);
    float4 wv4 = *(const float4*)&aw1[(size_t)h * 256 + c4];
    b.x += qb * wv4.x; b.y += qb * wv4.y; b.z += qb * wv4.z; b.w += qb * wv4.w;
  }
#undef RL
  float4 c04 = *(const float4*)&c0[c4];
  b.x += c04.x; b.y += c04.y; b.z += c04.z; b.w += c04.w;
  *(float4*)&qh[(size_t)p * 256 + c4] = b;
}

// ---------------------------------------------------------------------------
// K4: wave-per-query attention (R19 structure) + v-PREFETCH: the 20
// scattered v-gathers are issued during A1 (addresses ready via s_nb,
// values unused until phase C ~10K cycles later -> latency fully hidden
// under phase B's FMA stream). All register arrays static-indexed.
// ---------------------------------------------------------------------------
__global__ __launch_bounds__(256) void k_attn(
    const float* __restrict__ pos, const float* __restrict__ v,
    const int* __restrict__ idxbuf, const float* __restrict__ kh,
    const float* __restrict__ qh,
    const float* __restrict__ pw1, const float* __restrict__ pb1,
    const float* __restrict__ pw2, const float* __restrict__ pb2,
    const float* __restrict__ W2, const float* __restrict__ ab1,
    const float* __restrict__ aw2, const float* __restrict__ ab2,
    float* __restrict__ xout) {
  __shared__ float s_t1[4][KNB][64];   // 20 KB: [wave][n][h]
  __shared__ float s_sim[4][KNB];
  __shared__ int   s_nb[4][24];

  int tid = threadIdx.x;
  int wv = tid >> 6, lane = tid & 63;
  int i = blockIdx.x * 4 + wv;

  if (lane < KNB) s_nb[wv][lane] = idxbuf[i * KNB + lane];
  float px = pos[i * 3 + 0], py = pos[i * 3 + 1], pz = pos[i * 3 + 2];
  __syncthreads();

#define RL(x, l) __uint_as_float(__builtin_amdgcn_readlane(__float_as_uint(x), (l)))
  // A1: t1 -> registers + LDS; v prefetched alongside (used in phase C).
  float t1[KNB];
  float vnb[KNB];
  {
    float w1x = pw1[lane], w1y = pw1[64 + lane], w1z = pw1[128 + lane];
    float b1h = pb1[lane];
#pragma unroll
    for (int n = 0; n < KNB; n++) {
      int g = s_nb[wv][n];
      vnb[n] = v[(size_t)g * 64 + lane];
      float rx = px - pos[g * 3 + 0];
      float ry = py - pos[g * 3 + 1];
      float rz = pz - pos[g * 3 + 2];
      t1[n] = fmaxf(b1h + rx * w1x + ry * w1y + rz * w1z, 0.f);
      s_t1[wv][n][lane] = t1[n];
    }
  }
  __syncthreads();

  int col0 = lane * 4;
  float4 qh4 = *(const float4*)&qh[(size_t)i * 256 + col0];

  float4 b1v = *(const float4*)&ab1[col0];
  float4 w2v = *(const float4*)&aw2[col0];
  float ab2v = ab2[0];
#pragma unroll
  for (int pass = 0; pass < 4; pass++) {
    int nb0 = pass * 5;
    float acc[5][4];
#pragma unroll
    for (int n = 0; n < 5; n++) {
      int g = s_nb[wv][nb0 + n];
      float4 kv = *(const float4*)&kh[(size_t)g * 256 + col0];
      acc[n][0] = qh4.x - kv.x; acc[n][1] = qh4.y - kv.y;
      acc[n][2] = qh4.z - kv.z; acc[n][3] = qh4.w - kv.w;
    }
#pragma unroll 2
    for (int kc = 0; kc < 64; kc += 4) {
      float4 w0 = *(const float4*)&W2[(kc + 0) * 256 + col0];
      float4 w1 = *(const float4*)&W2[(kc + 1) * 256 + col0];
      float4 w2 = *(const float4*)&W2[(kc + 2) * 256 + col0];
      float4 w3 = *(const float4*)&W2[(kc + 3) * 256 + col0];
#pragma unroll
      for (int n = 0; n < 5; n++) {
        float4 iv = *(float4*)&s_t1[wv][nb0 + n][kc];
        acc[n][0] += iv.x * w0.x + iv.y * w1.x + iv.z * w2.x + iv.w * w3.x;
        acc[n][1] += iv.x * w0.y + iv.y * w1.y + iv.z * w2.y + iv.w * w3.y;
        acc[n][2] += iv.x * w0.z + iv.y * w1.z + iv.z * w2.z + iv.w * w3.z;
        acc[n][3] += iv.x * w0.w + iv.y * w1.w + iv.z * w2.w + iv.w * w3.w;
      }
    }
#pragma unroll
    for (int n = 0; n < 5; n++) {
      float s = fmaxf(acc[n][0] + b1v.x, 0.f) * w2v.x +
                fmaxf(acc[n][1] + b1v.y, 0.f) * w2v.y +
                fmaxf(acc[n][2] + b1v.z, 0.f) * w2v.z +
                fmaxf(acc[n][3] + b1v.w, 0.f) * w2v.w;
#pragma unroll
      for (int off = 32; off >= 1; off >>= 1) s += __shfl_xor(s, off);
      if (lane == 0) s_sim[wv][nb0 + n] = s + ab2v;
    }
  }
  __syncthreads();

  // C: softmax; out = sum an*vnb + (sum an*t1_n)@pw2 + pb2
  float mx = -3.402823466e38f;
#pragma unroll
  for (int n = 0; n < KNB; n++) mx = fmaxf(mx, s_sim[wv][n]);
  float sum = 0.f;
#pragma unroll
  for (int n = 0; n < KNB; n++) sum += expf(s_sim[wv][n] - mx);
  float inv = 1.f / sum;
  float o = 0.f;
  float sac = 0.f;
#pragma unroll
  for (int n = 0; n < KNB; n++) {
    float an = expf(s_sim[wv][n] - mx) * inv;
    o += an * vnb[n];
    sac += an * t1[n];
  }
  float r = pb2[lane];
#pragma unroll 8
  for (int j = 0; j < 64; j++) r += RL(sac, j) * pw2[j * 64 + lane];
#undef RL
  xout[(size_t)i * 64 + lane] = o + r;
}

// ---------------------------------------------------------------------------
// K5a: parallel max-pool stage 1 (R20, proven). Bit-exact (max assoc).
// ---------------------------------------------------------------------------
__global__ __launch_bounds__(256) void k_pool(const float* __restrict__ x,
                                              float* __restrict__ pmax) {
  __shared__ float red[4][64];
  int b = blockIdx.x >> 6, blk = blockIdx.x & 63;
  int tid = threadIdx.x;
  int c = tid & 63, pg = tid >> 6;
  int p0 = blk * 128;
  float mx = -3.402823466e38f;
  for (int p = pg; p < 128; p += 4)
    mx = fmaxf(mx, x[((size_t)b * NPTS + p0 + p) * 64 + c]);
  red[pg][c] = mx;
  __syncthreads();
  if (tid < 64)
    pmax[(size_t)blockIdx.x * 64 + c] =
        fmaxf(fmaxf(red[0][c], red[1][c]), fmaxf(red[2][c], red[3][c]));
}

// ---------------------------------------------------------------------------
// K5b: stage 2 — reduce 64 partials + fc1 + fc3 (R20, proven).
// ---------------------------------------------------------------------------
__global__ __launch_bounds__(256) void k_final2(const float* __restrict__ pmax,
                                                const float* __restrict__ fc1w,
                                                const float* __restrict__ fc1b,
                                                const float* __restrict__ fc3w,
                                                const float* __restrict__ fc3b,
                                                float* __restrict__ out) {
  __shared__ float red[4][64];
  __shared__ float m[64];
  __shared__ float h1[32];
  int b = blockIdx.x;
  int tid = threadIdx.x;
  int c = tid & 63, pg = tid >> 6;
  float mx = -3.402823466e38f;
  for (int blk = pg; blk < 64; blk += 4)
    mx = fmaxf(mx, pmax[(size_t)(b * 64 + blk) * 64 + c]);
  red[pg][c] = mx;
  __syncthreads();
  if (tid < 64)
    m[c] = fmaxf(fmaxf(red[0][c], red[1][c]), fmaxf(red[2][c], red[3][c]));
  __syncthreads();
  if (tid < 32) {
    float a = fc1b[tid];
#pragma unroll 8
    for (int k = 0; k < 64; k++) a += m[k] * fc1w[k * 32 + tid];
    h1[tid] = fmaxf(a, 0.f);
  }
  __syncthreads();
  if (tid < 3) {
    float a = fc3b[tid];
#pragma unroll
    for (int k = 0; k < 32; k++) a += h1[k] * fc3w[k * 3 + tid];
    out[b * 3 + tid] = a;
  }
}

// ---------------------------------------------------------------------------
// Workspace (peak ~44.8 MB):
//   idx @ 0 (1.31MB) | ptsT @ 1.5MB (0.2MB) | W2 @ 1.75MB (64KB) |
//   c0 @ 1.82MB (1KB) | pmax @ 1.86MB (32KB) | v @ 2MB (4.2MB) |
//   kh @ 6.5MB (16.8MB) | qh @ 23.5MB (16.8MB) | act @ 40.5MB (4.2MB)
// ---------------------------------------------------------------------------
extern "C" void kernel_launch(void* const* d_in, const int* in_sizes, int n_in,
                              void* d_out, int out_size, void* d_ws,
                              size_t ws_size, hipStream_t stream) {
  const float* pts    = (const float*)d_in[0];
  const float* conv_w = (const float*)d_in[1];
  const float* conv_b = (const float*)d_in[2];
  const float* fc1w = (const float*)d_in[21];
  const float* fc1b = (const float*)d_in[22];
  const float* fc3w = (const float*)d_in[23];
  const float* fc3b = (const float*)d_in[24];
  float* outp = (float*)d_out;

  char* ws = (char*)d_ws;
  int*   idx  = (int*)  (ws);
  float* ptsT = (float*)(ws + (size_t)1536 * 1024);
  float* W2   = (float*)(ws + (size_t)1792 * 1024);
  float* c0   = (float*)(ws + (size_t)1862 * 1024);
  float* pmax = (float*)(ws + (size_t)1900 * 1024);
  float* v    = (float*)(ws + (size_t)2 * 1048576);
  float* kh   = (float*)(ws + (size_t)6656 * 1024);
  float* qh   = (float*)(ws + (size_t)24064 * 1024);
  float* act  = (float*)(ws + (size_t)41472 * 1024);

  k_pose<<<(TOTAL * 3 + 255) / 256, 256, 0, stream>>>(pts, ptsT);
  k_conv<<<(TOTAL * 64 + 255) / 256, 256, 0, stream>>>(pts, conv_w, conv_b, act);
  k_knn<<<TOTAL / 4, 256, 0, stream>>>(ptsT, pts, idx);

  for (int layer = 0; layer < 2; layer++) {
    int base = 3 + layer * 9;
    const float* qkvw = (const float*)d_in[base + 0];
    const float* pw1  = (const float*)d_in[base + 1];
    const float* pb1  = (const float*)d_in[base + 2];
    const float* pw2  = (const float*)d_in[base + 3];
    const float* pb2  = (const float*)d_in[base + 4];
    const float* aw1  = (const float*)d_in[base + 5];
    const float* ab1  = (const float*)d_in[base + 6];
    const float* aw2  = (const float*)d_in[base + 7];
    const float* ab2  = (const float*)d_in[base + 8];
    k_w2<<<65, 256, 0, stream>>>(pw2, pb2, aw1, W2, c0);
    k_pre<<<TOTAL / 4, 256, 0, stream>>>(act, qkvw, aw1, c0, v, kh, qh);
    k_attn<<<TOTAL / 4, 256, 0, stream>>>(
        pts, v, idx, kh, qh, pw1, pb1, pw2, pb2, W2, ab1, aw2, ab2, act);
  }
  k_pool<<<BATCH * 64, 256, 0, stream>>>(act, pmax);
  k_final2<<<BATCH, 256, 0, stream>>>(pmax, fc1w, fc1b, fc3w, fc3b, outp);
}

// Round 22
// 1026.985 us; speedup vs baseline: 1.0248x; 1.0248x over previous
//
#include <hip/hip_runtime.h>
#include <cstdint>
#include <cstddef>

#define KNB 20
#define NPTS 8192
#define BATCH 2
#define TOTAL (BATCH * NPTS)

// ---------------------------------------------------------------------------
// K1: pointwise conv 3->64 + relu, FUSED with the pts->SoA transpose
// (threads with c<3 also write ptsT; same pts elements already loaded).
// ---------------------------------------------------------------------------
__global__ __launch_bounds__(256) void k_conv(const float* __restrict__ pts,
                                              const float* __restrict__ w,
                                              const float* __restrict__ b,
                                              float* __restrict__ x0,
                                              float* __restrict__ ptsT) {
  int gid = blockIdx.x * 256 + threadIdx.x;
  if (gid >= TOTAL * 64) return;
  int p = gid >> 6, c = gid & 63;
  float px = pts[p * 3 + 0], py = pts[p * 3 + 1], pz = pts[p * 3 + 2];
  float acc = b[c] + px * w[c] + py * w[64 + c] + pz * w[128 + c];
  x0[gid] = fmaxf(acc, 0.f);
  if (c < 3) {
    int bb = p >> 13, pp = p & (NPTS - 1);
    ptsT[((size_t)bb * 3 + c) * NPTS + pp] = pts[p * 3 + c];
  }
}

// ---------------------------------------------------------------------------
// K2: KNN v6 (R20, measured 289 µs, VALU 74% — REVERTED to single-chain
// insert; R21's two-segment variant paid BOTH divergent chains per wave:
// 30 steps vs 20 -> 327 µs). Barrier-free, no LDS, f32-bitonic tau,
// float4 candidate loads. Exact lax.top_k order.
// d2 via __fmul_rn/__fadd_rn: bit-identical to numpy's ((dx²+dy²)+dz²).
// ---------------------------------------------------------------------------
__global__ __launch_bounds__(256) void k_knn(const float* __restrict__ ptsT,
                                             const float* __restrict__ pts,
                                             int* __restrict__ idxbuf) {
  int tid = threadIdx.x;
  int wv = tid >> 6, lane = tid & 63;
  int q = blockIdx.x * 4 + wv;
  int bq = q >> 13;
  const float* px = ptsT + (size_t)bq * 3 * NPTS;
  const float* py = px + NPTS;
  const float* pz = py + NPTS;
  float qx = pts[q * 3 + 0], qy = pts[q * 3 + 1], qz = pts[q * 3 + 2];

  float dist[KNB];
  int id[KNB];
#pragma unroll
  for (int j = 0; j < KNB; j++) { dist[j] = 3.402823466e38f; id[j] = 0; }
  float tau = 3.402823466e38f;

#define INSERT(D2, CID)                                                      \
  if ((D2) <= tau && (D2) < dist[KNB - 1]) {                                 \
    int cid_ = (CID);                                                        \
    _Pragma("unroll")                                                        \
    for (int j = KNB - 1; j >= 0; j--) {                                     \
      bool cj = (D2) < dist[j];                                              \
      bool cjm1 = (j > 0) && ((D2) < dist[j - 1]);                           \
      if (cj) {                                                              \
        dist[j] = cjm1 ? dist[j - 1] : (D2);                                 \
        id[j]   = cjm1 ? id[j - 1]   : cid_;                                 \
      }                                                                      \
    }                                                                        \
  }

  for (int chunk = 0; chunk < 8; chunk++) {
    if (chunk) {
      // tau = 20th smallest of the 64 lane-head d2 values (f32 bitonic).
      float h = dist[0];
#pragma unroll
      for (int k = 2; k <= 64; k <<= 1) {
#pragma unroll
        for (int j = k >> 1; j > 0; j >>= 1) {
          float o = __shfl_xor(h, j);
          bool up = ((lane & k) == 0);
          bool lower = ((lane & j) == 0);
          bool takeMin = (up == lower);
          bool lt = h < o;
          h = (takeMin == lt) ? h : o;
        }
      }
      tau = __shfl(h, 19);
    }

    int base = chunk * 1024;
#pragma unroll
    for (int g = 0; g < 4; g++) {
      int cb = base + g * 256 + lane * 4;
      float4 x4 = *(const float4*)&px[cb];
      float4 y4 = *(const float4*)&py[cb];
      float4 z4 = *(const float4*)&pz[cb];
      float dx0 = qx - x4.x, dy0 = qy - y4.x, dz0 = qz - z4.x;
      float dx1 = qx - x4.y, dy1 = qy - y4.y, dz1 = qz - z4.y;
      float dx2 = qx - x4.z, dy2 = qy - y4.z, dz2 = qz - z4.z;
      float dx3 = qx - x4.w, dy3 = qy - y4.w, dz3 = qz - z4.w;
      float d0 = __fadd_rn(__fadd_rn(__fmul_rn(dx0, dx0), __fmul_rn(dy0, dy0)),
                           __fmul_rn(dz0, dz0));
      float d1 = __fadd_rn(__fadd_rn(__fmul_rn(dx1, dx1), __fmul_rn(dy1, dy1)),
                           __fmul_rn(dz1, dz1));
      float d2v = __fadd_rn(__fadd_rn(__fmul_rn(dx2, dx2), __fmul_rn(dy2, dy2)),
                            __fmul_rn(dz2, dz2));
      float d3 = __fadd_rn(__fadd_rn(__fmul_rn(dx3, dx3), __fmul_rn(dy3, dy3)),
                           __fmul_rn(dz3, dz3));
      INSERT(d0, cb + 0)
      INSERT(d1, cb + 1)
      INSERT(d2v, cb + 2)
      INSERT(d3, cb + 3)
    }
  }
#undef INSERT

  // 20-step cross-lane merge: min over packed (d2bits, cid) — exact
  // lax.top_k order (d2 asc, index asc).
  int bqoff = bq * NPTS;
  for (int step = 0; step < KNB; step++) {
    unsigned long long p =
        ((unsigned long long)__float_as_uint(dist[0]) << 32) | (unsigned)id[0];
    unsigned long long m = p;
#pragma unroll
    for (int off = 32; off >= 1; off >>= 1) {
      unsigned long long o = __shfl_xor(m, off);
      m = (o < m) ? o : m;
    }
    if (lane == 0) idxbuf[q * KNB + step] = bqoff + (int)(m & 0xffffffffULL);
    if (p == m) {
#pragma unroll
      for (int j = 0; j < KNB - 1; j++) { dist[j] = dist[j + 1]; id[j] = id[j + 1]; }
      dist[KNB - 1] = 3.402823466e38f;
    }
  }
}

// ---------------------------------------------------------------------------
// K3c: per-layer weight folding: W2 = pw2@aw1_bot, c0 = pb2@aw1_bot.
// ---------------------------------------------------------------------------
__global__ __launch_bounds__(256) void k_w2(const float* __restrict__ pw2,
                                            const float* __restrict__ pb2,
                                            const float* __restrict__ aw1,
                                            float* __restrict__ W2,
                                            float* __restrict__ c0) {
  int h = blockIdx.x, c = threadIdx.x;
  float a = 0.f;
  if (h < 64) {
#pragma unroll 8
    for (int j = 0; j < 64; j++)
      a += pw2[h * 64 + j] * aw1[(size_t)(64 + j) * 256 + c];
    W2[h * 256 + c] = a;
  } else {
#pragma unroll 8
    for (int j = 0; j < 64; j++)
      a += pb2[j] * aw1[(size_t)(64 + j) * 256 + c];
    c0[c] = a;
  }
}

// ---------------------------------------------------------------------------
// K3: FUSED qkv + kh + qh (R19, proven).
// ---------------------------------------------------------------------------
__global__ __launch_bounds__(256) void k_pre(const float* __restrict__ x,
                                             const float* __restrict__ w,
                                             const float* __restrict__ aw1,
                                             const float* __restrict__ c0,
                                             float* __restrict__ v,
                                             float* __restrict__ kh,
                                             float* __restrict__ qh) {
  int tid = threadIdx.x;
  int wv = tid >> 6, lane = tid & 63;
  int p = blockIdx.x * 4 + wv;
  const float* xr = x + (size_t)p * 64;

  float qa = 0.f, ka = 0.f, va = 0.f;
#pragma unroll 8
  for (int h = 0; h < 64; h++) {
    float xv = xr[h];
    qa += xv * w[h * 192 + lane];
    ka += xv * w[h * 192 + 64 + lane];
    va += xv * w[h * 192 + 128 + lane];
  }
  v[(size_t)p * 64 + lane] = va;

#define RL(x_, l_) __uint_as_float(__builtin_amdgcn_readlane(__float_as_uint(x_), (l_)))
  int c4 = lane * 4;
  float4 a = make_float4(0.f, 0.f, 0.f, 0.f);
#pragma unroll 8
  for (int h = 0; h < 64; h++) {
    float kb = RL(ka, h);
    float4 wv4 = *(const float4*)&aw1[(size_t)h * 256 + c4];
    a.x += kb * wv4.x; a.y += kb * wv4.y; a.z += kb * wv4.z; a.w += kb * wv4.w;
  }
  *(float4*)&kh[(size_t)p * 256 + c4] = a;

  float4 b = make_float4(0.f, 0.f, 0.f, 0.f);
#pragma unroll 8
  for (int h = 0; h < 64; h++) {
    float qb = RL(qa, h);
    float4 wv4 = *(const float4*)&aw1[(size_t)h * 256 + c4];
    b.x += qb * wv4.x; b.y += qb * wv4.y; b.z += qb * wv4.z; b.w += qb * wv4.w;
  }
#undef RL
  float4 c04 = *(const float4*)&c0[c4];
  b.x += c04.x; b.y += c04.y; b.z += c04.z; b.w += c04.w;
  *(float4*)&qh[(size_t)p * 256 + c4] = b;
}

// ---------------------------------------------------------------------------
// K4: wave-per-query attention (R21, kept — v-prefetch was a small win).
// ---------------------------------------------------------------------------
__global__ __launch_bounds__(256) void k_attn(
    const float* __restrict__ pos, const float* __restrict__ v,
    const int* __restrict__ idxbuf, const float* __restrict__ kh,
    const float* __restrict__ qh,
    const float* __restrict__ pw1, const float* __restrict__ pb1,
    const float* __restrict__ pw2, const float* __restrict__ pb2,
    const float* __restrict__ W2, const float* __restrict__ ab1,
    const float* __restrict__ aw2, const float* __restrict__ ab2,
    float* __restrict__ xout) {
  __shared__ float s_t1[4][KNB][64];   // 20 KB: [wave][n][h]
  __shared__ float s_sim[4][KNB];
  __shared__ int   s_nb[4][24];

  int tid = threadIdx.x;
  int wv = tid >> 6, lane = tid & 63;
  int i = blockIdx.x * 4 + wv;

  if (lane < KNB) s_nb[wv][lane] = idxbuf[i * KNB + lane];
  float px = pos[i * 3 + 0], py = pos[i * 3 + 1], pz = pos[i * 3 + 2];
  __syncthreads();

#define RL(x, l) __uint_as_float(__builtin_amdgcn_readlane(__float_as_uint(x), (l)))
  // A1: t1 -> registers + LDS; v prefetched alongside (used in phase C).
  float t1[KNB];
  float vnb[KNB];
  {
    float w1x = pw1[lane], w1y = pw1[64 + lane], w1z = pw1[128 + lane];
    float b1h = pb1[lane];
#pragma unroll
    for (int n = 0; n < KNB; n++) {
      int g = s_nb[wv][n];
      vnb[n] = v[(size_t)g * 64 + lane];
      float rx = px - pos[g * 3 + 0];
      float ry = py - pos[g * 3 + 1];
      float rz = pz - pos[g * 3 + 2];
      t1[n] = fmaxf(b1h + rx * w1x + ry * w1y + rz * w1z, 0.f);
      s_t1[wv][n][lane] = t1[n];
    }
  }
  __syncthreads();

  int col0 = lane * 4;
  float4 qh4 = *(const float4*)&qh[(size_t)i * 256 + col0];

  float4 b1v = *(const float4*)&ab1[col0];
  float4 w2v = *(const float4*)&aw2[col0];
  float ab2v = ab2[0];
#pragma unroll
  for (int pass = 0; pass < 4; pass++) {
    int nb0 = pass * 5;
    float acc[5][4];
#pragma unroll
    for (int n = 0; n < 5; n++) {
      int g = s_nb[wv][nb0 + n];
      float4 kv = *(const float4*)&kh[(size_t)g * 256 + col0];
      acc[n][0] = qh4.x - kv.x; acc[n][1] = qh4.y - kv.y;
      acc[n][2] = qh4.z - kv.z; acc[n][3] = qh4.w - kv.w;
    }
#pragma unroll 2
    for (int kc = 0; kc < 64; kc += 4) {
      float4 w0 = *(const float4*)&W2[(kc + 0) * 256 + col0];
      float4 w1 = *(const float4*)&W2[(kc + 1) * 256 + col0];
      float4 w2 = *(const float4*)&W2[(kc + 2) * 256 + col0];
      float4 w3 = *(const float4*)&W2[(kc + 3) * 256 + col0];
#pragma unroll
      for (int n = 0; n < 5; n++) {
        float4 iv = *(float4*)&s_t1[wv][nb0 + n][kc];
        acc[n][0] += iv.x * w0.x + iv.y * w1.x + iv.z * w2.x + iv.w * w3.x;
        acc[n][1] += iv.x * w0.y + iv.y * w1.y + iv.z * w2.y + iv.w * w3.y;
        acc[n][2] += iv.x * w0.z + iv.y * w1.z + iv.z * w2.z + iv.w * w3.z;
        acc[n][3] += iv.x * w0.w + iv.y * w1.w + iv.z * w2.w + iv.w * w3.w;
      }
    }
#pragma unroll
    for (int n = 0; n < 5; n++) {
      float s = fmaxf(acc[n][0] + b1v.x, 0.f) * w2v.x +
                fmaxf(acc[n][1] + b1v.y, 0.f) * w2v.y +
                fmaxf(acc[n][2] + b1v.z, 0.f) * w2v.z +
                fmaxf(acc[n][3] + b1v.w, 0.f) * w2v.w;
#pragma unroll
      for (int off = 32; off >= 1; off >>= 1) s += __shfl_xor(s, off);
      if (lane == 0) s_sim[wv][nb0 + n] = s + ab2v;
    }
  }
  __syncthreads();

  // C: softmax; out = sum an*vnb + (sum an*t1_n)@pw2 + pb2
  float mx = -3.402823466e38f;
#pragma unroll
  for (int n = 0; n < KNB; n++) mx = fmaxf(mx, s_sim[wv][n]);
  float sum = 0.f;
#pragma unroll
  for (int n = 0; n < KNB; n++) sum += expf(s_sim[wv][n] - mx);
  float inv = 1.f / sum;
  float o = 0.f;
  float sac = 0.f;
#pragma unroll
  for (int n = 0; n < KNB; n++) {
    float an = expf(s_sim[wv][n] - mx) * inv;
    o += an * vnb[n];
    sac += an * t1[n];
  }
  float r = pb2[lane];
#pragma unroll 8
  for (int j = 0; j < 64; j++) r += RL(sac, j) * pw2[j * 64 + lane];
#undef RL
  xout[(size_t)i * 64 + lane] = o + r;
}

// ---------------------------------------------------------------------------
// K5a: parallel max-pool stage 1 (R20, proven). Bit-exact (max assoc).
// ---------------------------------------------------------------------------
__global__ __launch_bounds__(256) void k_pool(const float* __restrict__ x,
                                              float* __restrict__ pmax) {
  __shared__ float red[4][64];
  int b = blockIdx.x >> 6, blk = blockIdx.x & 63;
  int tid = threadIdx.x;
  int c = tid & 63, pg = tid >> 6;
  int p0 = blk * 128;
  float mx = -3.402823466e38f;
  for (int p = pg; p < 128; p += 4)
    mx = fmaxf(mx, x[((size_t)b * NPTS + p0 + p) * 64 + c]);
  red[pg][c] = mx;
  __syncthreads();
  if (tid < 64)
    pmax[(size_t)blockIdx.x * 64 + c] =
        fmaxf(fmaxf(red[0][c], red[1][c]), fmaxf(red[2][c], red[3][c]));
}

// ---------------------------------------------------------------------------
// K5b: stage 2 — reduce 64 partials + fc1 + fc3 (R20, proven).
// ---------------------------------------------------------------------------
__global__ __launch_bounds__(256) void k_final2(const float* __restrict__ pmax,
                                                const float* __restrict__ fc1w,
                                                const float* __restrict__ fc1b,
                                                const float* __restrict__ fc3w,
                                                const float* __restrict__ fc3b,
                                                float* __restrict__ out) {
  __shared__ float red[4][64];
  __shared__ float m[64];
  __shared__ float h1[32];
  int b = blockIdx.x;
  int tid = threadIdx.x;
  int c = tid & 63, pg = tid >> 6;
  float mx = -3.402823466e38f;
  for (int blk = pg; blk < 64; blk += 4)
    mx = fmaxf(mx, pmax[(size_t)(b * 64 + blk) * 64 + c]);
  red[pg][c] = mx;
  __syncthreads();
  if (tid < 64)
    m[c] = fmaxf(fmaxf(red[0][c], red[1][c]), fmaxf(red[2][c], red[3][c]));
  __syncthreads();
  if (tid < 32) {
    float a = fc1b[tid];
#pragma unroll 8
    for (int k = 0; k < 64; k++) a += m[k] * fc1w[k * 32 + tid];
    h1[tid] = fmaxf(a, 0.f);
  }
  __syncthreads();
  if (tid < 3) {
    float a = fc3b[tid];
#pragma unroll
    for (int k = 0; k < 32; k++) a += h1[k] * fc3w[k * 3 + tid];
    out[b * 3 + tid] = a;
  }
}

// ---------------------------------------------------------------------------
// Workspace (peak ~44.8 MB):
//   idx @ 0 (1.31MB) | ptsT @ 1.5MB (0.2MB) | W2 @ 1.75MB (64KB) |
//   c0 @ 1.82MB (1KB) | pmax @ 1.86MB (32KB) | v @ 2MB (4.2MB) |
//   kh @ 6.5MB (16.8MB) | qh @ 23.5MB (16.8MB) | act @ 40.5MB (4.2MB)
// ---------------------------------------------------------------------------
extern "C" void kernel_launch(void* const* d_in, const int* in_sizes, int n_in,
                              void* d_out, int out_size, void* d_ws,
                              size_t ws_size, hipStream_t stream) {
  const float* pts    = (const float*)d_in[0];
  const float* conv_w = (const float*)d_in[1];
  const float* conv_b = (const float*)d_in[2];
  const float* fc1w = (const float*)d_in[21];
  const float* fc1b = (const float*)d_in[22];
  const float* fc3w = (const float*)d_in[23];
  const float* fc3b = (const float*)d_in[24];
  float* outp = (float*)d_out;

  char* ws = (char*)d_ws;
  int*   idx  = (int*)  (ws);
  float* ptsT = (float*)(ws + (size_t)1536 * 1024);
  float* W2   = (float*)(ws + (size_t)1792 * 1024);
  float* c0   = (float*)(ws + (size_t)1862 * 1024);
  float* pmax = (float*)(ws + (size_t)1900 * 1024);
  float* v    = (float*)(ws + (size_t)2 * 1048576);
  float* kh   = (float*)(ws + (size_t)6656 * 1024);
  float* qh   = (float*)(ws + (size_t)24064 * 1024);
  float* act  = (float*)(ws + (size_t)41472 * 1024);

  k_conv<<<(TOTAL * 64 + 255) / 256, 256, 0, stream>>>(pts, conv_w, conv_b,
                                                       act, ptsT);
  k_knn<<<TOTAL / 4, 256, 0, stream>>>(ptsT, pts, idx);

  for (int layer = 0; layer < 2; layer++) {
    int base = 3 + layer * 9;
    const float* qkvw = (const float*)d_in[base + 0];
    const float* pw1  = (const float*)d_in[base + 1];
    const float* pb1  = (const float*)d_in[base + 2];
    const float* pw2  = (const float*)d_in[base + 3];
    const float* pb2  = (const float*)d_in[base + 4];
    const float* aw1  = (const float*)d_in[base + 5];
    const float* ab1  = (const float*)d_in[base + 6];
    const float* aw2  = (const float*)d_in[base + 7];
    const float* ab2  = (const float*)d_in[base + 8];
    k_w2<<<65, 256, 0, stream>>>(pw2, pb2, aw1, W2, c0);
    k_pre<<<TOTAL / 4, 256, 0, stream>>>(act, qkvw, aw1, c0, v, kh, qh);
    k_attn<<<TOTAL / 4, 256, 0, stream>>>(
        pts, v, idx, kh, qh, pw1, pb1, pw2, pb2, W2, ab1, aw2, ab2, act);
  }
  k_pool<<<BATCH * 64, 256, 0, stream>>>(act, pmax);
  k_final2<<<BATCH, 256, 0, stream>>>(pmax, fc1w, fc1b, fc3w, fc3b, outp);
}

// Round 23
// 1005.791 us; speedup vs baseline: 1.0464x; 1.0211x over previous
//
#include <hip/hip_runtime.h>
#include <cstdint>
#include <cstddef>

#define KNB 20
#define NPTS 8192
#define BATCH 2
#define TOTAL (BATCH * NPTS)
#define NCELL 4096               // 16^3 grid per batch
#define SENT 0x7F800000FFFFFFFFULL  // d2=+inf, cid=~0 (u64-max real key bound)

// ---------------------------------------------------------------------------
// K1: pointwise conv 3->64 + relu
// ---------------------------------------------------------------------------
__global__ __launch_bounds__(256) void k_conv(const float* __restrict__ pts,
                                              const float* __restrict__ w,
                                              const float* __restrict__ b,
                                              float* __restrict__ x0) {
  int gid = blockIdx.x * 256 + threadIdx.x;
  if (gid >= TOTAL * 64) return;
  int p = gid >> 6, c = gid & 63;
  float px = pts[p * 3 + 0], py = pts[p * 3 + 1], pz = pts[p * 3 + 2];
  float acc = b[c] + px * w[c] + py * w[64 + c] + pz * w[128 + c];
  x0[gid] = fmaxf(acc, 0.f);
}

// ---------------------------------------------------------------------------
// Grid build (per batch, 16^3 cells, counting sort). All tiny (~25 µs).
// Scatter order within a cell is nondeterministic (atomics) — harmless:
// KNN uses packed (d2,cid) keys, so results are order-independent & exact.
// ---------------------------------------------------------------------------
__global__ __launch_bounds__(256) void k_zero(int* __restrict__ cnt) {
  int g = blockIdx.x * 256 + threadIdx.x;
  if (g < 2 * BATCH * NCELL) cnt[g] = 0;   // cnt + cnt2, contiguous
}

__global__ __launch_bounds__(256) void k_hist(const float* __restrict__ pts,
                                              int* __restrict__ cnt) {
  int p = blockIdx.x * 256 + threadIdx.x;
  if (p >= TOTAL) return;
  int b = p >> 13;
  int cx = min(15, (int)(pts[p * 3 + 0] * 16.f));
  int cy = min(15, (int)(pts[p * 3 + 1] * 16.f));
  int cz = min(15, (int)(pts[p * 3 + 2] * 16.f));
  atomicAdd(&cnt[b * NCELL + (cz * 16 + cy) * 16 + cx], 1);
}

__global__ __launch_bounds__(256) void k_scan(const int* __restrict__ cnt,
                                              int* __restrict__ cellStart) {
  __shared__ int ls[256];
  int b = blockIdx.x, t = threadIdx.x;
  const int* c = cnt + b * NCELL;
  int* cs = cellStart + b * (NCELL + 1);
  int base = t * 16;
  int s = 0;
#pragma unroll
  for (int i = 0; i < 16; i++) s += c[base + i];
  ls[t] = s;
  __syncthreads();
  for (int off = 1; off < 256; off <<= 1) {
    int v = (t >= off) ? ls[t - off] : 0;
    __syncthreads();
    ls[t] += v;
    __syncthreads();
  }
  int run = ls[t] - s;                  // exclusive prefix
#pragma unroll
  for (int i = 0; i < 16; i++) { cs[base + i] = run; run += c[base + i]; }
  if (t == 255) cs[NCELL] = run;        // sentinel = NPTS
}

__global__ __launch_bounds__(256) void k_scatter(
    const float* __restrict__ pts, int* __restrict__ cnt2,
    const int* __restrict__ cellStart, float* __restrict__ sx,
    float* __restrict__ sy, float* __restrict__ sz, int* __restrict__ sidx) {
  int p = blockIdx.x * 256 + threadIdx.x;
  if (p >= TOTAL) return;
  int b = p >> 13, pl = p & (NPTS - 1);
  float x = pts[p * 3 + 0], y = pts[p * 3 + 1], z = pts[p * 3 + 2];
  int cx = min(15, (int)(x * 16.f));
  int cy = min(15, (int)(y * 16.f));
  int cz = min(15, (int)(z * 16.f));
  int cell = (cz * 16 + cy) * 16 + cx;
  int pos = cellStart[b * (NCELL + 1) + cell] + atomicAdd(&cnt2[b * NCELL + cell], 1);
  size_t o = (size_t)b * NPTS + pos;
  sx[o] = x; sy[o] = y; sz[o] = z; sidx[o] = pl;
}

// ---------------------------------------------------------------------------
// K2: GRID KNN, wave per query, barrier-free, packed-u64 lists.
//  Main path: scan the 7x7x7 cell window; lane = (dz,dy) row -> one
//  contiguous sorted span (~14 pts); per-lane insert on packed (d2,cid)
//  (NOT wave-amplified). Terminate iff sorted_heads[19] < 0.0351
//  (< (3/16)^2 with safety margin for f32 d2 rounding + cell-binning
//  rounding): unscanned points have d2 > bound >= true 20th -> EXACT.
//  Fallback (corner queries / underfull windows, ~2%): restart with
//  tau = sorted[19] (>= true 20th) filter over all 8192 — exact, no dups.
//  Packed keys make order lax.top_k-exact regardless of scan order.
// ---------------------------------------------------------------------------
__global__ __launch_bounds__(256) void k_knn(
    const float* __restrict__ pts, const float* __restrict__ sx,
    const float* __restrict__ sy, const float* __restrict__ sz,
    const int* __restrict__ sidx, const int* __restrict__ cellStart,
    int* __restrict__ idxbuf) {
  int tid = threadIdx.x;
  int wv = tid >> 6, lane = tid & 63;
  int q = blockIdx.x * 4 + wv;
  int bq = q >> 13;
  const float* bx = sx + (size_t)bq * NPTS;
  const float* by = sy + (size_t)bq * NPTS;
  const float* bz = sz + (size_t)bq * NPTS;
  const int* bid = sidx + (size_t)bq * NPTS;
  const int* cs = cellStart + bq * (NCELL + 1);
  float qx = pts[q * 3 + 0], qy = pts[q * 3 + 1], qz = pts[q * 3 + 2];
  int cx = min(15, (int)(qx * 16.f));
  int cy = min(15, (int)(qy * 16.f));
  int cz = min(15, (int)(qz * 16.f));

  unsigned long long key[KNB];
#pragma unroll
  for (int j = 0; j < KNB; j++) key[j] = SENT;

#define INS(KK)                                                              \
  if ((KK) < key[KNB - 1]) {                                                 \
    _Pragma("unroll")                                                        \
    for (int j = KNB - 1; j >= 0; j--) {                                     \
      bool cj = (KK) < key[j];                                               \
      bool cjm1 = (j > 0) && ((KK) < key[j - 1]);                            \
      if (cj) key[j] = cjm1 ? key[j - 1] : (KK);                             \
    }                                                                        \
  }

  // main: R=3 window; lane < 49 owns one (dz,dy) row
  if (lane < 49) {
    int dz = lane / 7 - 3, dy = lane % 7 - 3;
    int z = cz + dz, y = cy + dy;
    if (z >= 0 && z < 16 && y >= 0 && y < 16) {
      int x0 = cx - 3; if (x0 < 0) x0 = 0;
      int x1 = cx + 3; if (x1 > 15) x1 = 15;
      int rb = (z * 16 + y) * 16;
      int s = cs[rb + x0], e = cs[rb + x1 + 1];
      for (int i = s; i < e; i++) {
        float dxv = qx - bx[i], dyv = qy - by[i], dzv = qz - bz[i];
        float d2 = __fadd_rn(__fadd_rn(__fmul_rn(dxv, dxv), __fmul_rn(dyv, dyv)),
                             __fmul_rn(dzv, dzv));
        unsigned long long kk =
            ((unsigned long long)__float_as_uint(d2) << 32) | (unsigned)bid[i];
        INS(kk)
      }
    }
  }

  // termination: sorted[19] of head d2 values (f32 bitonic; sentinels=+inf)
  float h = __uint_as_float((unsigned)(key[0] >> 32));
#pragma unroll
  for (int k = 2; k <= 64; k <<= 1) {
#pragma unroll
    for (int j = k >> 1; j > 0; j >>= 1) {
      float o = __shfl_xor(h, j);
      bool up = ((lane & k) == 0);
      bool lower = ((lane & j) == 0);
      bool takeMin = (up == lower);
      bool lt = h < o;
      h = (takeMin == lt) ? h : o;
    }
  }
  float tau19 = __shfl(h, 19);

  if (!(tau19 < 0.0351f)) {
    // fallback: exact rescan of all 8192 with tau filter, from scratch
#pragma unroll
    for (int j = 0; j < KNB; j++) key[j] = SENT;
    for (int g = 0; g < 32; g++) {
      int i0 = g * 256 + lane * 4;
      float4 x4 = *(const float4*)&bx[i0];
      float4 y4 = *(const float4*)&by[i0];
      float4 z4 = *(const float4*)&bz[i0];
#define FB(C, XX, YY, ZZ)                                                    \
      {                                                                      \
        float dxv = qx - (XX), dyv = qy - (YY), dzv = qz - (ZZ);             \
        float d2 = __fadd_rn(__fadd_rn(__fmul_rn(dxv, dxv),                  \
                                       __fmul_rn(dyv, dyv)),                 \
                             __fmul_rn(dzv, dzv));                           \
        if (d2 <= tau19) {                                                   \
          unsigned long long kk =                                            \
              ((unsigned long long)__float_as_uint(d2) << 32) |              \
              (unsigned)bid[i0 + (C)];                                       \
          INS(kk)                                                            \
        }                                                                    \
      }
      FB(0, x4.x, y4.x, z4.x)
      FB(1, x4.y, y4.y, z4.y)
      FB(2, x4.z, y4.z, z4.z)
      FB(3, x4.w, y4.w, z4.w)
#undef FB
    }
  }
#undef INS

  // 20-step cross-lane merge: min over packed (d2bits, cid) — exact
  // lax.top_k order (d2 asc, index asc). >=20 real keys guaranteed
  // (main path: tau19 finite => 20 finite heads; fallback: 8192 scanned).
  int bqoff = bq * NPTS;
  for (int step = 0; step < KNB; step++) {
    unsigned long long p = key[0];
    unsigned long long m = p;
#pragma unroll
    for (int off = 32; off >= 1; off >>= 1) {
      unsigned long long o = __shfl_xor(m, off);
      m = (o < m) ? o : m;
    }
    if (lane == 0) idxbuf[q * KNB + step] = bqoff + (int)(m & 0xffffffffULL);
    if (p == m) {
#pragma unroll
      for (int j = 0; j < KNB - 1; j++) key[j] = key[j + 1];
      key[KNB - 1] = SENT;
    }
  }
}

// ---------------------------------------------------------------------------
// K3c: per-layer weight folding: W2 = pw2@aw1_bot, c0 = pb2@aw1_bot.
// ---------------------------------------------------------------------------
__global__ __launch_bounds__(256) void k_w2(const float* __restrict__ pw2,
                                            const float* __restrict__ pb2,
                                            const float* __restrict__ aw1,
                                            float* __restrict__ W2,
                                            float* __restrict__ c0) {
  int h = blockIdx.x, c = threadIdx.x;
  float a = 0.f;
  if (h < 64) {
#pragma unroll 8
    for (int j = 0; j < 64; j++)
      a += pw2[h * 64 + j] * aw1[(size_t)(64 + j) * 256 + c];
    W2[h * 256 + c] = a;
  } else {
#pragma unroll 8
    for (int j = 0; j < 64; j++)
      a += pb2[j] * aw1[(size_t)(64 + j) * 256 + c];
    c0[c] = a;
  }
}

// ---------------------------------------------------------------------------
// K3: FUSED qkv + kh + qh (R19, proven).
// ---------------------------------------------------------------------------
__global__ __launch_bounds__(256) void k_pre(const float* __restrict__ x,
                                             const float* __restrict__ w,
                                             const float* __restrict__ aw1,
                                             const float* __restrict__ c0,
                                             float* __restrict__ v,
                                             float* __restrict__ kh,
                                             float* __restrict__ qh) {
  int tid = threadIdx.x;
  int wv = tid >> 6, lane = tid & 63;
  int p = blockIdx.x * 4 + wv;
  const float* xr = x + (size_t)p * 64;

  float qa = 0.f, ka = 0.f, va = 0.f;
#pragma unroll 8
  for (int h = 0; h < 64; h++) {
    float xv = xr[h];
    qa += xv * w[h * 192 + lane];
    ka += xv * w[h * 192 + 64 + lane];
    va += xv * w[h * 192 + 128 + lane];
  }
  v[(size_t)p * 64 + lane] = va;

#define RL(x_, l_) __uint_as_float(__builtin_amdgcn_readlane(__float_as_uint(x_), (l_)))
  int c4 = lane * 4;
  float4 a = make_float4(0.f, 0.f, 0.f, 0.f);
#pragma unroll 8
  for (int h = 0; h < 64; h++) {
    float kb = RL(ka, h);
    float4 wv4 = *(const float4*)&aw1[(size_t)h * 256 + c4];
    a.x += kb * wv4.x; a.y += kb * wv4.y; a.z += kb * wv4.z; a.w += kb * wv4.w;
  }
  *(float4*)&kh[(size_t)p * 256 + c4] = a;

  float4 b = make_float4(0.f, 0.f, 0.f, 0.f);
#pragma unroll 8
  for (int h = 0; h < 64; h++) {
    float qb = RL(qa, h);
    float4 wv4 = *(const float4*)&aw1[(size_t)h * 256 + c4];
    b.x += qb * wv4.x; b.y += qb * wv4.y; b.z += qb * wv4.z; b.w += qb * wv4.w;
  }
#undef RL
  float4 c04 = *(const float4*)&c0[c4];
  b.x += c04.x; b.y += c04.y; b.z += c04.z; b.w += c04.w;
  *(float4*)&qh[(size_t)p * 256 + c4] = b;
}

// ---------------------------------------------------------------------------
// K4: wave-per-query attention (R21/R22, proven).
// ---------------------------------------------------------------------------
__global__ __launch_bounds__(256) void k_attn(
    const float* __restrict__ pos, const float* __restrict__ v,
    const int* __restrict__ idxbuf, const float* __restrict__ kh,
    const float* __restrict__ qh,
    const float* __restrict__ pw1, const float* __restrict__ pb1,
    const float* __restrict__ pw2, const float* __restrict__ pb2,
    const float* __restrict__ W2, const float* __restrict__ ab1,
    const float* __restrict__ aw2, const float* __restrict__ ab2,
    float* __restrict__ xout) {
  __shared__ float s_t1[4][KNB][64];   // 20 KB: [wave][n][h]
  __shared__ float s_sim[4][KNB];
  __shared__ int   s_nb[4][24];

  int tid = threadIdx.x;
  int wv = tid >> 6, lane = tid & 63;
  int i = blockIdx.x * 4 + wv;

  if (lane < KNB) s_nb[wv][lane] = idxbuf[i * KNB + lane];
  float px = pos[i * 3 + 0], py = pos[i * 3 + 1], pz = pos[i * 3 + 2];
  __syncthreads();

#define RL(x, l) __uint_as_float(__builtin_amdgcn_readlane(__float_as_uint(x), (l)))
  // A1: t1 -> registers + LDS; v prefetched alongside (used in phase C).
  float t1[KNB];
  float vnb[KNB];
  {
    float w1x = pw1[lane], w1y = pw1[64 + lane], w1z = pw1[128 + lane];
    float b1h = pb1[lane];
#pragma unroll
    for (int n = 0; n < KNB; n++) {
      int g = s_nb[wv][n];
      vnb[n] = v[(size_t)g * 64 + lane];
      float rx = px - pos[g * 3 + 0];
      float ry = py - pos[g * 3 + 1];
      float rz = pz - pos[g * 3 + 2];
      t1[n] = fmaxf(b1h + rx * w1x + ry * w1y + rz * w1z, 0.f);
      s_t1[wv][n][lane] = t1[n];
    }
  }
  __syncthreads();

  int col0 = lane * 4;
  float4 qh4 = *(const float4*)&qh[(size_t)i * 256 + col0];

  float4 b1v = *(const float4*)&ab1[col0];
  float4 w2v = *(const float4*)&aw2[col0];
  float ab2v = ab2[0];
#pragma unroll
  for (int pass = 0; pass < 4; pass++) {
    int nb0 = pass * 5;
    float acc[5][4];
#pragma unroll
    for (int n = 0; n < 5; n++) {
      int g = s_nb[wv][nb0 + n];
      float4 kv = *(const float4*)&kh[(size_t)g * 256 + col0];
      acc[n][0] = qh4.x - kv.x; acc[n][1] = qh4.y - kv.y;
      acc[n][2] = qh4.z - kv.z; acc[n][3] = qh4.w - kv.w;
    }
#pragma unroll 2
    for (int kc = 0; kc < 64; kc += 4) {
      float4 w0 = *(const float4*)&W2[(kc + 0) * 256 + col0];
      float4 w1 = *(const float4*)&W2[(kc + 1) * 256 + col0];
      float4 w2 = *(const float4*)&W2[(kc + 2) * 256 + col0];
      float4 w3 = *(const float4*)&W2[(kc + 3) * 256 + col0];
#pragma unroll
      for (int n = 0; n < 5; n++) {
        float4 iv = *(float4*)&s_t1[wv][nb0 + n][kc];
        acc[n][0] += iv.x * w0.x + iv.y * w1.x + iv.z * w2.x + iv.w * w3.x;
        acc[n][1] += iv.x * w0.y + iv.y * w1.y + iv.z * w2.y + iv.w * w3.y;
        acc[n][2] += iv.x * w0.z + iv.y * w1.z + iv.z * w2.z + iv.w * w3.z;
        acc[n][3] += iv.x * w0.w + iv.y * w1.w + iv.z * w2.w + iv.w * w3.w;
      }
    }
#pragma unroll
    for (int n = 0; n < 5; n++) {
      float s = fmaxf(acc[n][0] + b1v.x, 0.f) * w2v.x +
                fmaxf(acc[n][1] + b1v.y, 0.f) * w2v.y +
                fmaxf(acc[n][2] + b1v.z, 0.f) * w2v.z +
                fmaxf(acc[n][3] + b1v.w, 0.f) * w2v.w;
#pragma unroll
      for (int off = 32; off >= 1; off >>= 1) s += __shfl_xor(s, off);
      if (lane == 0) s_sim[wv][nb0 + n] = s + ab2v;
    }
  }
  __syncthreads();

  // C: softmax; out = sum an*vnb + (sum an*t1_n)@pw2 + pb2
  float mx = -3.402823466e38f;
#pragma unroll
  for (int n = 0; n < KNB; n++) mx = fmaxf(mx, s_sim[wv][n]);
  float sum = 0.f;
#pragma unroll
  for (int n = 0; n < KNB; n++) sum += expf(s_sim[wv][n] - mx);
  float inv = 1.f / sum;
  float o = 0.f;
  float sac = 0.f;
#pragma unroll
  for (int n = 0; n < KNB; n++) {
    float an = expf(s_sim[wv][n] - mx) * inv;
    o += an * vnb[n];
    sac += an * t1[n];
  }
  float r = pb2[lane];
#pragma unroll 8
  for (int j = 0; j < 64; j++) r += RL(sac, j) * pw2[j * 64 + lane];
#undef RL
  xout[(size_t)i * 64 + lane] = o + r;
}

// ---------------------------------------------------------------------------
// K5a/K5b: parallel max-pool + head (R20, proven; bit-exact).
// ---------------------------------------------------------------------------
__global__ __launch_bounds__(256) void k_pool(const float* __restrict__ x,
                                              float* __restrict__ pmax) {
  __shared__ float red[4][64];
  int b = blockIdx.x >> 6, blk = blockIdx.x & 63;
  int tid = threadIdx.x;
  int c = tid & 63, pg = tid >> 6;
  int p0 = blk * 128;
  float mx = -3.402823466e38f;
  for (int p = pg; p < 128; p += 4)
    mx = fmaxf(mx, x[((size_t)b * NPTS + p0 + p) * 64 + c]);
  red[pg][c] = mx;
  __syncthreads();
  if (tid < 64)
    pmax[(size_t)blockIdx.x * 64 + c] =
        fmaxf(fmaxf(red[0][c], red[1][c]), fmaxf(red[2][c], red[3][c]));
}

__global__ __launch_bounds__(256) void k_final2(const float* __restrict__ pmax,
                                                const float* __restrict__ fc1w,
                                                const float* __restrict__ fc1b,
                                                const float* __restrict__ fc3w,
                                                const float* __restrict__ fc3b,
                                                float* __restrict__ out) {
  __shared__ float red[4][64];
  __shared__ float m[64];
  __shared__ float h1[32];
  int b = blockIdx.x;
  int tid = threadIdx.x;
  int c = tid & 63, pg = tid >> 6;
  float mx = -3.402823466e38f;
  for (int blk = pg; blk < 64; blk += 4)
    mx = fmaxf(mx, pmax[(size_t)(b * 64 + blk) * 64 + c]);
  red[pg][c] = mx;
  __syncthreads();
  if (tid < 64)
    m[c] = fmaxf(fmaxf(red[0][c], red[1][c]), fmaxf(red[2][c], red[3][c]));
  __syncthreads();
  if (tid < 32) {
    float a = fc1b[tid];
#pragma unroll 8
    for (int k = 0; k < 64; k++) a += m[k] * fc1w[k * 32 + tid];
    h1[tid] = fmaxf(a, 0.f);
  }
  __syncthreads();
  if (tid < 3) {
    float a = fc3b[tid];
#pragma unroll
    for (int k = 0; k < 32; k++) a += h1[k] * fc3w[k * 3 + tid];
    out[b * 3 + tid] = a;
  }
}

// ---------------------------------------------------------------------------
// Workspace (peak ~44.8 MB, same as R19-proven):
//   idx @ 0 (1.31MB) | sx/sy/sz/sidx @ 1408/1472/1536/1600KB (64KB each)
//   W2 @ 1664KB (64KB) | c0 @ 1728KB (1KB) | pmax @ 1732KB (32KB)
//   cellStart @ 1764KB (33KB) | cnt+cnt2 @ 1800KB (64KB)
//   v @ 2MB (4.2MB) | kh @ 6.5MB (16.8MB) | qh @ 23.5MB (16.8MB)
//   act @ 40.5MB (4.2MB)
// ---------------------------------------------------------------------------
extern "C" void kernel_launch(void* const* d_in, const int* in_sizes, int n_in,
                              void* d_out, int out_size, void* d_ws,
                              size_t ws_size, hipStream_t stream) {
  const float* pts    = (const float*)d_in[0];
  const float* conv_w = (const float*)d_in[1];
  const float* conv_b = (const float*)d_in[2];
  const float* fc1w = (const float*)d_in[21];
  const float* fc1b = (const float*)d_in[22];
  const float* fc3w = (const float*)d_in[23];
  const float* fc3b = (const float*)d_in[24];
  float* outp = (float*)d_out;

  char* ws = (char*)d_ws;
  int*   idx   = (int*)  (ws);
  float* sx    = (float*)(ws + (size_t)1408 * 1024);
  float* sy    = (float*)(ws + (size_t)1472 * 1024);
  float* sz    = (float*)(ws + (size_t)1536 * 1024);
  int*   sidx  = (int*)  (ws + (size_t)1600 * 1024);
  float* W2    = (float*)(ws + (size_t)1664 * 1024);
  float* c0    = (float*)(ws + (size_t)1728 * 1024);
  float* pmax  = (float*)(ws + (size_t)1732 * 1024);
  int*   cellS = (int*)  (ws + (size_t)1764 * 1024);
  int*   cnt   = (int*)  (ws + (size_t)1800 * 1024);   // cnt + cnt2 (64KB)
  int*   cnt2  = cnt + BATCH * NCELL;
  float* v     = (float*)(ws + (size_t)2 * 1048576);
  float* kh    = (float*)(ws + (size_t)6656 * 1024);
  float* qh    = (float*)(ws + (size_t)24064 * 1024);
  float* act   = (float*)(ws + (size_t)41472 * 1024);

  k_conv<<<(TOTAL * 64 + 255) / 256, 256, 0, stream>>>(pts, conv_w, conv_b, act);
  k_zero<<<(2 * BATCH * NCELL + 255) / 256, 256, 0, stream>>>(cnt);
  k_hist<<<(TOTAL + 255) / 256, 256, 0, stream>>>(pts, cnt);
  k_scan<<<BATCH, 256, 0, stream>>>(cnt, cellS);
  k_scatter<<<(TOTAL + 255) / 256, 256, 0, stream>>>(pts, cnt2, cellS, sx, sy,
                                                     sz, sidx);
  k_knn<<<TOTAL / 4, 256, 0, stream>>>(pts, sx, sy, sz, sidx, cellS, idx);

  for (int layer = 0; layer < 2; layer++) {
    int base = 3 + layer * 9;
    const float* qkvw = (const float*)d_in[base + 0];
    const float* pw1  = (const float*)d_in[base + 1];
    const float* pb1  = (const float*)d_in[base + 2];
    const float* pw2  = (const float*)d_in[base + 3];
    const float* pb2  = (const float*)d_in[base + 4];
    const float* aw1  = (const float*)d_in[base + 5];
    const float* ab1  = (const float*)d_in[base + 6];
    const float* aw2  = (const float*)d_in[base + 7];
    const float* ab2  = (const float*)d_in[base + 8];
    k_w2<<<65, 256, 0, stream>>>(pw2, pb2, aw1, W2, c0);
    k_pre<<<TOTAL / 4, 256, 0, stream>>>(act, qkvw, aw1, c0, v, kh, qh);
    k_attn<<<TOTAL / 4, 256, 0, stream>>>(
        pts, v, idx, kh, qh, pw1, pb1, pw2, pb2, W2, ab1, aw2, ab2, act);
  }
  k_pool<<<BATCH * 64, 256, 0, stream>>>(act, pmax);
  k_final2<<<BATCH, 256, 0, stream>>>(pmax, fc1w, fc1b, fc3w, fc3b, outp);
}